// Round 2
// baseline (368.250 us; speedup 1.0000x reference)
//
#include <hip/hip_runtime.h>
#include <hip/hip_bf16.h>

#define D_IN  64
#define D_OUT 128

// ---------------------------------------------------------------------------
// K1: count in-degree (excluding self-loop) via int atomics
// ---------------------------------------------------------------------------
__global__ __launch_bounds__(256) void k_count_deg(const int* __restrict__ dst,
                                                   int* __restrict__ deg, int E) {
    int e = blockIdx.x * 256 + threadIdx.x;
    if (e < E) atomicAdd(&deg[dst[e]], 1);
}

// ---------------------------------------------------------------------------
// K2a: per-block exclusive scan of deg -> row (local), block sums -> bsum.
//      Also computes dinv[i] = rsqrt(deg+1)  (self-loop included; deg+1 >= 1).
// ---------------------------------------------------------------------------
__global__ __launch_bounds__(256) void k_scan_local(const int* __restrict__ deg,
                                                    float* __restrict__ dinv,
                                                    int* __restrict__ row,
                                                    int* __restrict__ bsum, int N) {
    __shared__ int sd[256];
    int i = blockIdx.x * 256 + threadIdx.x;
    int v = (i < N) ? deg[i] : 0;
    if (i < N) dinv[i] = rsqrtf((float)(v + 1));
    sd[threadIdx.x] = v;
    __syncthreads();
    for (int off = 1; off < 256; off <<= 1) {
        int t = (threadIdx.x >= off) ? sd[threadIdx.x - off] : 0;
        __syncthreads();
        sd[threadIdx.x] += t;
        __syncthreads();
    }
    if (i < N) row[i] = sd[threadIdx.x] - v;   // exclusive
    if (threadIdx.x == 255) bsum[blockIdx.x] = sd[255];
}

// K2b: exclusive scan of block sums (nblk <= 256; N <= 65536 here)
__global__ __launch_bounds__(256) void k_scan_bsum(int* __restrict__ bsum, int nblk) {
    __shared__ int sd[256];
    int v = (threadIdx.x < nblk) ? bsum[threadIdx.x] : 0;
    sd[threadIdx.x] = v;
    __syncthreads();
    for (int off = 1; off < 256; off <<= 1) {
        int t = (threadIdx.x >= off) ? sd[threadIdx.x - off] : 0;
        __syncthreads();
        sd[threadIdx.x] += t;
        __syncthreads();
    }
    if (threadIdx.x < nblk) bsum[threadIdx.x] = sd[threadIdx.x] - v;  // exclusive
}

// K2c: add scanned block offsets back
__global__ __launch_bounds__(256) void k_scan_add(int* __restrict__ row,
                                                  const int* __restrict__ bsum, int N) {
    int i = blockIdx.x * 256 + threadIdx.x;
    if (i < N) row[i] += bsum[blockIdx.x];
}

// ---------------------------------------------------------------------------
// K3: fill CSR edge array. After this, row[n] == row_start[n] + deg[n] == end.
// ---------------------------------------------------------------------------
__global__ __launch_bounds__(256) void k_fill_edges(const int* __restrict__ src,
                                                    const int* __restrict__ dst,
                                                    int* __restrict__ row,
                                                    int* __restrict__ esrc, int E) {
    int e = blockIdx.x * 256 + threadIdx.x;
    if (e < E) {
        int d = dst[e];
        int pos = atomicAdd(&row[d], 1);
        esrc[pos] = src[e];
    }
}

// ---------------------------------------------------------------------------
// K4: dual GEMM  xw = x@W  and  resid = x@res_W + res_b.
//     W and res_W staged in LDS (exactly 64 KiB). One wave per node,
//     lane l owns output columns {2l, 2l+1}. Grid-stride over nodes.
// ---------------------------------------------------------------------------
__global__ __launch_bounds__(256) void k_gemm_dual(const float* __restrict__ x,
                                                   const float* __restrict__ W,
                                                   const float* __restrict__ rW,
                                                   const float* __restrict__ rb,
                                                   float* __restrict__ xw,
                                                   float* __restrict__ resid, int N) {
    __shared__ float sW[D_IN * D_OUT];
    __shared__ float sR[D_IN * D_OUT];
    for (int i = threadIdx.x; i < D_IN * D_OUT; i += 256) {
        sW[i] = W[i];
        sR[i] = rW[i];
    }
    __syncthreads();
    int wave = threadIdx.x >> 6, lane = threadIdx.x & 63;
    int gw = blockIdx.x * 4 + wave;
    int stride = gridDim.x * 4;
    float2 rbv = *(const float2*)&rb[lane * 2];
    for (int n = gw; n < N; n += stride) {
        const float* xr = &x[(size_t)n * D_IN];
        float2 a0 = make_float2(0.f, 0.f), a1 = make_float2(0.f, 0.f);
#pragma unroll
        for (int k = 0; k < D_IN; k++) {
            float xv = xr[k];  // wave-uniform broadcast load (L1)
            float2 w = *(const float2*)&sW[k * D_OUT + lane * 2];
            float2 r = *(const float2*)&sR[k * D_OUT + lane * 2];
            a0.x = fmaf(xv, w.x, a0.x);
            a0.y = fmaf(xv, w.y, a0.y);
            a1.x = fmaf(xv, r.x, a1.x);
            a1.y = fmaf(xv, r.y, a1.y);
        }
        *(float2*)&xw[(size_t)n * D_OUT + lane * 2] = a0;
        a1.x += rbv.x;
        a1.y += rbv.y;
        *(float2*)&resid[(size_t)n * D_OUT + lane * 2] = a1;
    }
}

// ---------------------------------------------------------------------------
// K5: gather-aggregate + LayerNorm + residual + SiLU. One wave per node.
// ---------------------------------------------------------------------------
__global__ __launch_bounds__(256) void k_aggregate(const int* __restrict__ esrc,
                                                   const int* __restrict__ rowend,
                                                   const int* __restrict__ deg,
                                                   const float* __restrict__ dinv,
                                                   const float* __restrict__ xw,
                                                   const float* __restrict__ resid,
                                                   const float* __restrict__ b,
                                                   const float* __restrict__ lnw,
                                                   const float* __restrict__ lnb,
                                                   float* __restrict__ out, int N) {
    int wave = threadIdx.x >> 6, lane = threadIdx.x & 63;
    int n = blockIdx.x * 4 + wave;
    if (n >= N) return;

    float dn = dinv[n];
    float2 xwn = *(const float2*)&xw[(size_t)n * D_OUT + lane * 2];
    float2 bb = *(const float2*)&b[lane * 2];
    float selfw = dn * dn;
    float2 acc;
    acc.x = bb.x + xwn.x * selfw;
    acc.y = bb.y + xwn.y * selfw;

    int end = rowend[n];
    int cnt = deg[n];
    for (int j = end - cnt; j < end; ++j) {
        int s = esrc[j];               // wave-uniform
        float w = dinv[s] * dn;
        float2 v = *(const float2*)&xw[(size_t)s * D_OUT + lane * 2];
        acc.x = fmaf(v.x, w, acc.x);
        acc.y = fmaf(v.y, w, acc.y);
    }

    // LayerNorm across 128 (2 per lane, 64 lanes)
    float s1 = acc.x + acc.y;
    float s2 = acc.x * acc.x + acc.y * acc.y;
#pragma unroll
    for (int m = 1; m < 64; m <<= 1) {
        s1 += __shfl_xor(s1, m);
        s2 += __shfl_xor(s2, m);
    }
    float mu = s1 * (1.f / 128.f);
    float var = s2 * (1.f / 128.f) - mu * mu;
    float inv = rsqrtf(var + 1e-5f);

    float2 lw = *(const float2*)&lnw[lane * 2];
    float2 lb = *(const float2*)&lnb[lane * 2];
    float2 r = *(const float2*)&resid[(size_t)n * D_OUT + lane * 2];
    float y0 = (acc.x - mu) * inv * lw.x + lb.x + r.x;
    float y1 = (acc.y - mu) * inv * lw.y + lb.y + r.y;
    float o0 = y0 / (1.f + expf(-y0));
    float o1 = y1 / (1.f + expf(-y1));
    *(float2*)&out[(size_t)n * D_OUT + lane * 2] = make_float2(o0, o1);
}

// ---------------------------------------------------------------------------
extern "C" void kernel_launch(void* const* d_in, const int* in_sizes, int n_in,
                              void* d_out, int out_size, void* d_ws, size_t ws_size,
                              hipStream_t stream) {
    const float* x = (const float*)d_in[0];
    const int* ei = (const int*)d_in[1];   // harness converts integer inputs to int32
    const float* W = (const float*)d_in[2];
    const float* b = (const float*)d_in[3];
    const float* lnw = (const float*)d_in[4];
    const float* lnb = (const float*)d_in[5];
    const float* rW = (const float*)d_in[6];
    const float* rb = (const float*)d_in[7];
    float* out = (float*)d_out;

    int N = in_sizes[0] / D_IN;
    int E = in_sizes[1] / 2;
    const int* esrc_in = ei;
    const int* edst_in = ei + E;

    // workspace carve-up (all 4-byte types)
    float* xw = (float*)d_ws;                   // N*128
    float* resid = xw + (size_t)N * D_OUT;      // N*128
    float* dinv = resid + (size_t)N * D_OUT;    // N
    int* deg = (int*)(dinv + N);                // N
    int* row = deg + N;                         // N
    int* bsum = row + N;                        // 256
    int* esrc = bsum + 256;                     // E

    hipMemsetAsync(deg, 0, (size_t)N * sizeof(int), stream);

    int eblk = (E + 255) / 256;
    int nblk = (N + 255) / 256;

    k_count_deg<<<eblk, 256, 0, stream>>>(edst_in, deg, E);
    k_scan_local<<<nblk, 256, 0, stream>>>(deg, dinv, row, bsum, N);
    k_scan_bsum<<<1, 256, 0, stream>>>(bsum, nblk);
    k_scan_add<<<nblk, 256, 0, stream>>>(row, bsum, N);
    k_fill_edges<<<eblk, 256, 0, stream>>>(esrc_in, edst_in, row, esrc, E);
    k_gemm_dual<<<1024, 256, 0, stream>>>(x, W, rW, rb, xw, resid, N);
    k_aggregate<<<(N + 3) / 4, 256, 0, stream>>>(esrc, row, deg, dinv, xw, resid,
                                                 b, lnw, lnb, out, N);
}

// Round 3
// 306.311 us; speedup vs baseline: 1.2022x; 1.2022x over previous
//
#include <hip/hip_runtime.h>
#include <hip/hip_bf16.h>

#define D_IN  64
#define D_OUT 128

// ---------------------------------------------------------------------------
// K1: count in-degree (excluding self-loop) via int atomics
// ---------------------------------------------------------------------------
__global__ __launch_bounds__(256) void k_count_deg(const int* __restrict__ dst,
                                                   int* __restrict__ deg, int E) {
    int e = blockIdx.x * 256 + threadIdx.x;
    if (e < E) atomicAdd(&deg[dst[e]], 1);
}

// ---------------------------------------------------------------------------
// K2a: per-block exclusive scan of deg -> row (local), block sums -> bsum.
//      Also dinv[i] = rsqrt(deg+1) (self-loop included).
// ---------------------------------------------------------------------------
__global__ __launch_bounds__(256) void k_scan_local(const int* __restrict__ deg,
                                                    float* __restrict__ dinv,
                                                    int* __restrict__ row,
                                                    int* __restrict__ bsum, int N) {
    __shared__ int sd[256];
    int i = blockIdx.x * 256 + threadIdx.x;
    int v = (i < N) ? deg[i] : 0;
    if (i < N) dinv[i] = rsqrtf((float)(v + 1));
    sd[threadIdx.x] = v;
    __syncthreads();
    for (int off = 1; off < 256; off <<= 1) {
        int t = (threadIdx.x >= off) ? sd[threadIdx.x - off] : 0;
        __syncthreads();
        sd[threadIdx.x] += t;
        __syncthreads();
    }
    if (i < N) row[i] = sd[threadIdx.x] - v;   // exclusive
    if (threadIdx.x == 255) bsum[blockIdx.x] = sd[255];
}

// K2b: exclusive scan of block sums (nblk <= 256)
__global__ __launch_bounds__(256) void k_scan_bsum(int* __restrict__ bsum, int nblk) {
    __shared__ int sd[256];
    int v = (threadIdx.x < nblk) ? bsum[threadIdx.x] : 0;
    sd[threadIdx.x] = v;
    __syncthreads();
    for (int off = 1; off < 256; off <<= 1) {
        int t = (threadIdx.x >= off) ? sd[threadIdx.x - off] : 0;
        __syncthreads();
        sd[threadIdx.x] += t;
        __syncthreads();
    }
    if (threadIdx.x < nblk) bsum[threadIdx.x] = sd[threadIdx.x] - v;  // exclusive
}

// K2c: add scanned block offsets back
__global__ __launch_bounds__(256) void k_scan_add(int* __restrict__ row,
                                                  const int* __restrict__ bsum, int N) {
    int i = blockIdx.x * 256 + threadIdx.x;
    if (i < N) row[i] += bsum[blockIdx.x];
}

// ---------------------------------------------------------------------------
// K3: fill CSR edge array. Afterwards row[n] == start[n] + deg[n] == end.
// ---------------------------------------------------------------------------
__global__ __launch_bounds__(256) void k_fill_edges(const int* __restrict__ src,
                                                    const int* __restrict__ dst,
                                                    int* __restrict__ row,
                                                    int* __restrict__ esrc, int E) {
    int e = blockIdx.x * 256 + threadIdx.x;
    if (e < E) {
        int d = dst[e];
        int pos = atomicAdd(&row[d], 1);
        esrc[pos] = src[e];
    }
}

// ---------------------------------------------------------------------------
// K4: gather-aggregate in D_IN=64 space (A_hat x). One wave per node, lane = col.
//     agg[n] = dn * ( sum_s dinv[s]*x[s] + dn*x[n] )
// ---------------------------------------------------------------------------
__global__ __launch_bounds__(256) void k_gather(const int* __restrict__ esrc,
                                                const int* __restrict__ rowend,
                                                const int* __restrict__ deg,
                                                const float* __restrict__ dinv,
                                                const float* __restrict__ x,
                                                float* __restrict__ agg, int N) {
    int wave = threadIdx.x >> 6, lane = threadIdx.x & 63;
    int n = blockIdx.x * 4 + wave;
    if (n >= N) return;
    float dn = dinv[n];
    float acc = x[(size_t)n * D_IN + lane] * dn;   // self-loop (pre outer dn)
    int end = rowend[n];
    int cnt = deg[n];
    for (int j = end - cnt; j < end; ++j) {
        int s = esrc[j];                 // wave-uniform
        float w = dinv[s];               // wave-uniform
        acc = fmaf(w, x[(size_t)s * D_IN + lane], acc);  // 256B coalesced gather
    }
    agg[(size_t)n * D_IN + lane] = acc * dn;
}

// ---------------------------------------------------------------------------
// K5: fused dual GEMM + LayerNorm + residual + SiLU.
//     block = 1024 (16 waves). LDS: W (32K) + res_W (32K) + row scratch (32K).
//     Each wave: 4 nodes per iter; lane owns output cols {2l, 2l+1}.
//     Row values broadcast via uniform-address LDS reads (conflict-free).
// ---------------------------------------------------------------------------
#define GW 16   // waves per block
__global__ __launch_bounds__(1024) void k_gemm_ln(const float* __restrict__ agg,
                                                  const float* __restrict__ x,
                                                  const float* __restrict__ W,
                                                  const float* __restrict__ rW,
                                                  const float* __restrict__ b,
                                                  const float* __restrict__ rb,
                                                  const float* __restrict__ lnw,
                                                  const float* __restrict__ lnb,
                                                  float* __restrict__ out, int N) {
    __shared__ float sW[D_IN * D_OUT];        // 32 KB
    __shared__ float sR[D_IN * D_OUT];        // 32 KB
    __shared__ float rows[GW][8][D_IN];       // 32 KB: per wave 4 agg rows + 4 x rows

    for (int i = threadIdx.x; i < D_IN * D_OUT; i += 1024) {
        sW[i] = W[i];
        sR[i] = rW[i];
    }
    __syncthreads();

    int wave = threadIdx.x >> 6, lane = threadIdx.x & 63;
    float2 bb  = *(const float2*)&b[lane * 2];
    float2 rbv = *(const float2*)&rb[lane * 2];
    float2 lwv = *(const float2*)&lnw[lane * 2];
    float2 lbv = *(const float2*)&lnb[lane * 2];

    int groups = (N + 63) >> 6;               // 64 nodes per block-iter
    for (int g = blockIdx.x; g < groups; g += gridDim.x) {
        int n0 = g * 64 + wave * 4;
        // stage this wave's 4 agg rows + 4 x rows into private LDS scratch
#pragma unroll
        for (int i = 0; i < 4; i++) {
            int n = n0 + i;
            rows[wave][i][lane]     = (n < N) ? agg[(size_t)n * D_IN + lane] : 0.f;
            rows[wave][4 + i][lane] = (n < N) ? x[(size_t)n * D_IN + lane] : 0.f;
        }
        // wave-private LDS region: no barrier needed (compiler inserts lgkmcnt)

        float2 aw0 = {0.f, 0.f}, aw1 = {0.f, 0.f}, aw2 = {0.f, 0.f}, aw3 = {0.f, 0.f};
        float2 ar0 = {0.f, 0.f}, ar1 = {0.f, 0.f}, ar2 = {0.f, 0.f}, ar3 = {0.f, 0.f};

#pragma unroll 4
        for (int k = 0; k < D_IN; k++) {
            float2 w = *(const float2*)&sW[k * D_OUT + lane * 2];
            float2 r = *(const float2*)&sR[k * D_OUT + lane * 2];
            float a0 = rows[wave][0][k], a1 = rows[wave][1][k];
            float a2 = rows[wave][2][k], a3 = rows[wave][3][k];
            float x0 = rows[wave][4][k], x1 = rows[wave][5][k];
            float x2 = rows[wave][6][k], x3 = rows[wave][7][k];
            aw0.x = fmaf(a0, w.x, aw0.x); aw0.y = fmaf(a0, w.y, aw0.y);
            aw1.x = fmaf(a1, w.x, aw1.x); aw1.y = fmaf(a1, w.y, aw1.y);
            aw2.x = fmaf(a2, w.x, aw2.x); aw2.y = fmaf(a2, w.y, aw2.y);
            aw3.x = fmaf(a3, w.x, aw3.x); aw3.y = fmaf(a3, w.y, aw3.y);
            ar0.x = fmaf(x0, r.x, ar0.x); ar0.y = fmaf(x0, r.y, ar0.y);
            ar1.x = fmaf(x1, r.x, ar1.x); ar1.y = fmaf(x1, r.y, ar1.y);
            ar2.x = fmaf(x2, r.x, ar2.x); ar2.y = fmaf(x2, r.y, ar2.y);
            ar3.x = fmaf(x3, r.x, ar3.x); ar3.y = fmaf(x3, r.y, ar3.y);
        }

        // epilogue: LN + residual + SiLU, per node
#pragma unroll
        for (int i = 0; i < 4; i++) {
            int n = n0 + i;
            if (n >= N) continue;                   // wave-uniform branch
            float2 aw = (i == 0) ? aw0 : (i == 1) ? aw1 : (i == 2) ? aw2 : aw3;
            float2 ar = (i == 0) ? ar0 : (i == 1) ? ar1 : (i == 2) ? ar2 : ar3;
            float tx = aw.x + bb.x, ty = aw.y + bb.y;
            float s1 = tx + ty;
            float s2 = tx * tx + ty * ty;
#pragma unroll
            for (int m = 1; m < 64; m <<= 1) {
                s1 += __shfl_xor(s1, m);
                s2 += __shfl_xor(s2, m);
            }
            float mu = s1 * (1.f / 128.f);
            float var = s2 * (1.f / 128.f) - mu * mu;
            float inv = rsqrtf(var + 1e-5f);
            float y0 = (tx - mu) * inv * lwv.x + lbv.x + ar.x + rbv.x;
            float y1 = (ty - mu) * inv * lwv.y + lbv.y + ar.y + rbv.y;
            float o0 = y0 / (1.f + expf(-y0));
            float o1 = y1 / (1.f + expf(-y1));
            *(float2*)&out[(size_t)n * D_OUT + lane * 2] = make_float2(o0, o1);
        }
    }
}

// ---------------------------------------------------------------------------
extern "C" void kernel_launch(void* const* d_in, const int* in_sizes, int n_in,
                              void* d_out, int out_size, void* d_ws, size_t ws_size,
                              hipStream_t stream) {
    const float* x = (const float*)d_in[0];
    const int* ei = (const int*)d_in[1];   // harness converts integer inputs to int32
    const float* W = (const float*)d_in[2];
    const float* b = (const float*)d_in[3];
    const float* lnw = (const float*)d_in[4];
    const float* lnb = (const float*)d_in[5];
    const float* rW = (const float*)d_in[6];
    const float* rb = (const float*)d_in[7];
    float* out = (float*)d_out;

    int N = in_sizes[0] / D_IN;
    int E = in_sizes[1] / 2;
    const int* esrc_in = ei;
    const int* edst_in = ei + E;

    // workspace carve-up (all 4-byte types)
    float* agg = (float*)d_ws;                  // N*64
    float* dinv = agg + (size_t)N * D_IN;       // N
    int* deg = (int*)(dinv + N);                // N
    int* row = deg + N;                         // N
    int* bsum = row + N;                        // 256
    int* esrc = bsum + 256;                     // E

    hipMemsetAsync(deg, 0, (size_t)N * sizeof(int), stream);

    int eblk = (E + 255) / 256;
    int nblk = (N + 255) / 256;

    k_count_deg<<<eblk, 256, 0, stream>>>(edst_in, deg, E);
    k_scan_local<<<nblk, 256, 0, stream>>>(deg, dinv, row, bsum, N);
    k_scan_bsum<<<1, 256, 0, stream>>>(bsum, nblk);
    k_scan_add<<<nblk, 256, 0, stream>>>(row, bsum, N);
    k_fill_edges<<<eblk, 256, 0, stream>>>(esrc_in, edst_in, row, esrc, E);
    k_gather<<<(N + 3) / 4, 256, 0, stream>>>(esrc, row, deg, dinv, x, agg, N);
    k_gemm_ln<<<256, 1024, 0, stream>>>(agg, x, W, rW, b, rb, lnw, lnb, out, N);
}

// Round 6
// 257.565 us; speedup vs baseline: 1.4297x; 1.1893x over previous
//
#include <hip/hip_runtime.h>
#include <hip/hip_bf16.h>

#define D_IN  64
#define D_OUT 128

// ---------------------------------------------------------------------------
// K1: count in-degree (excluding self-loop) via int atomics
// ---------------------------------------------------------------------------
__global__ __launch_bounds__(256) void k_count_deg(const int* __restrict__ dst,
                                                   int* __restrict__ deg, int E) {
    int e = blockIdx.x * 256 + threadIdx.x;
    if (e < E) atomicAdd(&deg[dst[e]], 1);
}

// ---------------------------------------------------------------------------
// K2a: per-block exclusive scan of PADDED deg ((deg+7)&~7) -> row, block sums.
//      Also dinv[i] = rsqrt(deg+1) (self-loop included).
//      Padded starts are 8-aligned => float4 pair loads are 16B-aligned.
// ---------------------------------------------------------------------------
__global__ __launch_bounds__(256) void k_scan_local(const int* __restrict__ deg,
                                                    float* __restrict__ dinv,
                                                    int* __restrict__ row,
                                                    int* __restrict__ bsum, int N) {
    __shared__ int sd[256];
    int i = blockIdx.x * 256 + threadIdx.x;
    int v = (i < N) ? deg[i] : 0;
    if (i < N) dinv[i] = rsqrtf((float)(v + 1));
    int vp = (v + 7) & ~7;               // padded degree
    sd[threadIdx.x] = vp;
    __syncthreads();
    for (int off = 1; off < 256; off <<= 1) {
        int t = (threadIdx.x >= off) ? sd[threadIdx.x - off] : 0;
        __syncthreads();
        sd[threadIdx.x] += t;
        __syncthreads();
    }
    if (i < N) row[i] = sd[threadIdx.x] - vp;   // exclusive (padded)
    if (threadIdx.x == 255) bsum[blockIdx.x] = sd[255];
}

// K2b: exclusive scan of block sums (nblk <= 256)
__global__ __launch_bounds__(256) void k_scan_bsum(int* __restrict__ bsum, int nblk) {
    __shared__ int sd[256];
    int v = (threadIdx.x < nblk) ? bsum[threadIdx.x] : 0;
    sd[threadIdx.x] = v;
    __syncthreads();
    for (int off = 1; off < 256; off <<= 1) {
        int t = (threadIdx.x >= off) ? sd[threadIdx.x - off] : 0;
        __syncthreads();
        sd[threadIdx.x] += t;
        __syncthreads();
    }
    if (threadIdx.x < nblk) bsum[threadIdx.x] = sd[threadIdx.x] - v;  // exclusive
}

// K2c: add scanned block offsets back
__global__ __launch_bounds__(256) void k_scan_add(int* __restrict__ row,
                                                  const int* __restrict__ bsum, int N) {
    int i = blockIdx.x * 256 + threadIdx.x;
    if (i < N) row[i] += bsum[blockIdx.x];
}

// ---------------------------------------------------------------------------
// K3: fill CSR with packed (src, dinv[src]) pairs. Dummy/padding slots remain
//     zero from the memset (src=0, w=0.0 -> contributes exactly 0).
//     Afterwards row[n] == padded_start[n] + deg[n].
// ---------------------------------------------------------------------------
__global__ __launch_bounds__(256) void k_fill_edges(const int* __restrict__ src,
                                                    const int* __restrict__ dst,
                                                    const float* __restrict__ dinv,
                                                    int* __restrict__ row,
                                                    int2* __restrict__ ep, int E) {
    int e = blockIdx.x * 256 + threadIdx.x;
    if (e < E) {
        int d = dst[e];
        int s = src[e];
        int pos = atomicAdd(&row[d], 1);
        ep[pos] = make_int2(s, __float_as_int(dinv[s]));
    }
}

// ---------------------------------------------------------------------------
// K4: gather-aggregate in D_IN=64 space. One wave per node, lane = column.
//     Unroll-8 over padded edge list: 4 uniform float4 pair-loads, then
//     8 independent row-gathers in flight, then 8 FMAs.
// ---------------------------------------------------------------------------
__global__ __launch_bounds__(256) void k_gather(const int* __restrict__ rowend,
                                                const int* __restrict__ deg,
                                                const float* __restrict__ dinv,
                                                const float4* __restrict__ ep4,
                                                const float* __restrict__ x,
                                                float* __restrict__ agg, int N) {
    int wave = threadIdx.x >> 6, lane = threadIdx.x & 63;
    int n = blockIdx.x * 4 + wave;
    if (n >= N) return;
    float dn = dinv[n];
    float acc = x[(size_t)n * D_IN + lane] * dn;   // self-loop (outer dn applied at end)
    int end = rowend[n];
    int cnt = deg[n];
    int start = end - cnt;                          // 8-aligned padded start
    int iters = (cnt + 7) >> 3;
    const float4* p = ep4 + (start >> 1);           // 2 pairs per float4
    for (int it = 0; it < iters; ++it, p += 4) {
        float4 p01 = p[0], p23 = p[1], p45 = p[2], p67 = p[3];
        int s0 = __float_as_int(p01.x), s1 = __float_as_int(p01.z);
        int s2 = __float_as_int(p23.x), s3 = __float_as_int(p23.z);
        int s4 = __float_as_int(p45.x), s5 = __float_as_int(p45.z);
        int s6 = __float_as_int(p67.x), s7 = __float_as_int(p67.z);
        float v0 = x[(size_t)s0 * D_IN + lane];
        float v1 = x[(size_t)s1 * D_IN + lane];
        float v2 = x[(size_t)s2 * D_IN + lane];
        float v3 = x[(size_t)s3 * D_IN + lane];
        float v4 = x[(size_t)s4 * D_IN + lane];
        float v5 = x[(size_t)s5 * D_IN + lane];
        float v6 = x[(size_t)s6 * D_IN + lane];
        float v7 = x[(size_t)s7 * D_IN + lane];
        acc = fmaf(p01.y, v0, acc);
        acc = fmaf(p01.w, v1, acc);
        acc = fmaf(p23.y, v2, acc);
        acc = fmaf(p23.w, v3, acc);
        acc = fmaf(p45.y, v4, acc);
        acc = fmaf(p45.w, v5, acc);
        acc = fmaf(p67.y, v6, acc);
        acc = fmaf(p67.w, v7, acc);
    }
    agg[(size_t)n * D_IN + lane] = acc * dn;
}

// ---------------------------------------------------------------------------
// K5: fused dual GEMM + LayerNorm + residual + SiLU.
//     block = 1024 (16 waves). LDS: W (32K) + res_W (32K) + row scratch (32K).
// ---------------------------------------------------------------------------
#define GW 16   // waves per block
__global__ __launch_bounds__(1024) void k_gemm_ln(const float* __restrict__ agg,
                                                  const float* __restrict__ x,
                                                  const float* __restrict__ W,
                                                  const float* __restrict__ rW,
                                                  const float* __restrict__ b,
                                                  const float* __restrict__ rb,
                                                  const float* __restrict__ lnw,
                                                  const float* __restrict__ lnb,
                                                  float* __restrict__ out, int N) {
    __shared__ float sW[D_IN * D_OUT];        // 32 KB
    __shared__ float sR[D_IN * D_OUT];        // 32 KB
    __shared__ float rows[GW][8][D_IN];       // 32 KB: per wave 4 agg rows + 4 x rows

    for (int i = threadIdx.x; i < D_IN * D_OUT; i += 1024) {
        sW[i] = W[i];
        sR[i] = rW[i];
    }
    __syncthreads();

    int wave = threadIdx.x >> 6, lane = threadIdx.x & 63;
    float2 bb  = *(const float2*)&b[lane * 2];
    float2 rbv = *(const float2*)&rb[lane * 2];
    float2 lwv = *(const float2*)&lnw[lane * 2];
    float2 lbv = *(const float2*)&lnb[lane * 2];

    int groups = (N + 63) >> 6;               // 64 nodes per block-iter
    for (int g = blockIdx.x; g < groups; g += gridDim.x) {
        int n0 = g * 64 + wave * 4;
#pragma unroll
        for (int i = 0; i < 4; i++) {
            int n = n0 + i;
            rows[wave][i][lane]     = (n < N) ? agg[(size_t)n * D_IN + lane] : 0.f;
            rows[wave][4 + i][lane] = (n < N) ? x[(size_t)n * D_IN + lane] : 0.f;
        }
        // wave-private LDS region: no barrier needed (lgkmcnt ordering)

        float2 aw0 = {0.f, 0.f}, aw1 = {0.f, 0.f}, aw2 = {0.f, 0.f}, aw3 = {0.f, 0.f};
        float2 ar0 = {0.f, 0.f}, ar1 = {0.f, 0.f}, ar2 = {0.f, 0.f}, ar3 = {0.f, 0.f};

#pragma unroll 4
        for (int k = 0; k < D_IN; k++) {
            float2 w = *(const float2*)&sW[k * D_OUT + lane * 2];
            float2 r = *(const float2*)&sR[k * D_OUT + lane * 2];
            float a0 = rows[wave][0][k], a1 = rows[wave][1][k];
            float a2 = rows[wave][2][k], a3 = rows[wave][3][k];
            float x0 = rows[wave][4][k], x1 = rows[wave][5][k];
            float x2 = rows[wave][6][k], x3 = rows[wave][7][k];
            aw0.x = fmaf(a0, w.x, aw0.x); aw0.y = fmaf(a0, w.y, aw0.y);
            aw1.x = fmaf(a1, w.x, aw1.x); aw1.y = fmaf(a1, w.y, aw1.y);
            aw2.x = fmaf(a2, w.x, aw2.x); aw2.y = fmaf(a2, w.y, aw2.y);
            aw3.x = fmaf(a3, w.x, aw3.x); aw3.y = fmaf(a3, w.y, aw3.y);
            ar0.x = fmaf(x0, r.x, ar0.x); ar0.y = fmaf(x0, r.y, ar0.y);
            ar1.x = fmaf(x1, r.x, ar1.x); ar1.y = fmaf(x1, r.y, ar1.y);
            ar2.x = fmaf(x2, r.x, ar2.x); ar2.y = fmaf(x2, r.y, ar2.y);
            ar3.x = fmaf(x3, r.x, ar3.x); ar3.y = fmaf(x3, r.y, ar3.y);
        }

#pragma unroll
        for (int i = 0; i < 4; i++) {
            int n = n0 + i;
            if (n >= N) continue;                   // wave-uniform branch
            float2 aw = (i == 0) ? aw0 : (i == 1) ? aw1 : (i == 2) ? aw2 : aw3;
            float2 ar = (i == 0) ? ar0 : (i == 1) ? ar1 : (i == 2) ? ar2 : ar3;
            float tx = aw.x + bb.x, ty = aw.y + bb.y;
            float s1 = tx + ty;
            float s2 = tx * tx + ty * ty;
#pragma unroll
            for (int m = 1; m < 64; m <<= 1) {
                s1 += __shfl_xor(s1, m);
                s2 += __shfl_xor(s2, m);
            }
            float mu = s1 * (1.f / 128.f);
            float var = s2 * (1.f / 128.f) - mu * mu;
            float inv = rsqrtf(var + 1e-5f);
            float y0 = (tx - mu) * inv * lwv.x + lbv.x + ar.x + rbv.x;
            float y1 = (ty - mu) * inv * lwv.y + lbv.y + ar.y + rbv.y;
            float o0 = y0 / (1.f + expf(-y0));
            float o1 = y1 / (1.f + expf(-y1));
            *(float2*)&out[(size_t)n * D_OUT + lane * 2] = make_float2(o0, o1);
        }
    }
}

// ---------------------------------------------------------------------------
extern "C" void kernel_launch(void* const* d_in, const int* in_sizes, int n_in,
                              void* d_out, int out_size, void* d_ws, size_t ws_size,
                              hipStream_t stream) {
    const float* x = (const float*)d_in[0];
    const int* ei = (const int*)d_in[1];   // harness converts integer inputs to int32
    const float* W = (const float*)d_in[2];
    const float* b = (const float*)d_in[3];
    const float* lnw = (const float*)d_in[4];
    const float* lnb = (const float*)d_in[5];
    const float* rW = (const float*)d_in[6];
    const float* rb = (const float*)d_in[7];
    float* out = (float*)d_out;

    int N = in_sizes[0] / D_IN;
    int E = in_sizes[1] / 2;
    const int* esrc_in = ei;
    const int* edst_in = ei + E;

    // workspace carve-up (all 4-byte types)
    float* agg = (float*)d_ws;                  // N*64
    float* dinv = agg + (size_t)N * D_IN;       // N
    int* deg = (int*)(dinv + N);                // N
    int* row = deg + N;                         // N
    int* bsum = row + N;                        // 256
    int2* ep = (int2*)(bsum + 256);             // E + 7N + 8 pairs (padded CSR)

    size_t ep_pairs = (size_t)E + 7u * (size_t)N + 8u;

    hipMemsetAsync(deg, 0, (size_t)N * sizeof(int), stream);
    hipMemsetAsync(ep, 0, ep_pairs * sizeof(int2), stream);  // zero padding slots

    int eblk = (E + 255) / 256;
    int nblk = (N + 255) / 256;

    k_count_deg<<<eblk, 256, 0, stream>>>(edst_in, deg, E);
    k_scan_local<<<nblk, 256, 0, stream>>>(deg, dinv, row, bsum, N);
    k_scan_bsum<<<1, 256, 0, stream>>>(bsum, nblk);
    k_scan_add<<<nblk, 256, 0, stream>>>(row, bsum, N);
    k_fill_edges<<<eblk, 256, 0, stream>>>(esrc_in, edst_in, dinv, row, ep, E);
    k_gather<<<(N + 3) / 4, 256, 0, stream>>>(row, deg, dinv, (const float4*)ep, x, agg, N);
    k_gemm_ln<<<256, 1024, 0, stream>>>(agg, x, W, rW, b, rb, lnw, lnb, out, N);
}

// Round 7
// 220.092 us; speedup vs baseline: 1.6732x; 1.1703x over previous
//
#include <hip/hip_runtime.h>
#include <hip/hip_bf16.h>

#define D_IN  64
#define D_OUT 128

typedef float  f32x4  __attribute__((ext_vector_type(4)));
typedef short  bf16x8 __attribute__((ext_vector_type(8)));

__device__ inline unsigned short f2bf(float f) {   // RTN-even f32 -> bf16
    unsigned u = __float_as_uint(f);
    u += 0x7FFFu + ((u >> 16) & 1u);
    return (unsigned short)(u >> 16);
}

// ---------------------------------------------------------------------------
// K1: count in-degree (excluding self-loop) via int atomics
// ---------------------------------------------------------------------------
__global__ __launch_bounds__(256) void k_count_deg(const int* __restrict__ dst,
                                                   int* __restrict__ deg, int E) {
    int e = blockIdx.x * 256 + threadIdx.x;
    if (e < E) atomicAdd(&deg[dst[e]], 1);
}

// ---------------------------------------------------------------------------
// K2a: per-block exclusive scan of PADDED deg ((deg+7)&~7) -> row, block sums.
//      Also dinv[i] = rsqrt(deg+1) (self-loop included).
// ---------------------------------------------------------------------------
__global__ __launch_bounds__(256) void k_scan_local(const int* __restrict__ deg,
                                                    float* __restrict__ dinv,
                                                    int* __restrict__ row,
                                                    int* __restrict__ bsum, int N) {
    __shared__ int sd[256];
    int i = blockIdx.x * 256 + threadIdx.x;
    int v = (i < N) ? deg[i] : 0;
    if (i < N) dinv[i] = rsqrtf((float)(v + 1));
    int vp = (v + 7) & ~7;               // padded degree
    sd[threadIdx.x] = vp;
    __syncthreads();
    for (int off = 1; off < 256; off <<= 1) {
        int t = (threadIdx.x >= off) ? sd[threadIdx.x - off] : 0;
        __syncthreads();
        sd[threadIdx.x] += t;
        __syncthreads();
    }
    if (i < N) row[i] = sd[threadIdx.x] - vp;   // exclusive (padded)
    if (threadIdx.x == 255) bsum[blockIdx.x] = sd[255];
}

// K2b: exclusive scan of block sums (nblk <= 256)
__global__ __launch_bounds__(256) void k_scan_bsum(int* __restrict__ bsum, int nblk) {
    __shared__ int sd[256];
    int v = (threadIdx.x < nblk) ? bsum[threadIdx.x] : 0;
    sd[threadIdx.x] = v;
    __syncthreads();
    for (int off = 1; off < 256; off <<= 1) {
        int t = (threadIdx.x >= off) ? sd[threadIdx.x - off] : 0;
        __syncthreads();
        sd[threadIdx.x] += t;
        __syncthreads();
    }
    if (threadIdx.x < nblk) bsum[threadIdx.x] = sd[threadIdx.x] - v;  // exclusive
}

// K2c: add scanned block offsets back
__global__ __launch_bounds__(256) void k_scan_add(int* __restrict__ row,
                                                  const int* __restrict__ bsum, int N) {
    int i = blockIdx.x * 256 + threadIdx.x;
    if (i < N) row[i] += bsum[blockIdx.x];
}

// ---------------------------------------------------------------------------
// K3: fill CSR with packed (src, dinv[src]) pairs. Padding slots stay zero.
// ---------------------------------------------------------------------------
__global__ __launch_bounds__(256) void k_fill_edges(const int* __restrict__ src,
                                                    const int* __restrict__ dst,
                                                    const float* __restrict__ dinv,
                                                    int* __restrict__ row,
                                                    int2* __restrict__ ep, int E) {
    int e = blockIdx.x * 256 + threadIdx.x;
    if (e < E) {
        int d = dst[e];
        int s = src[e];
        int pos = atomicAdd(&row[d], 1);
        ep[pos] = make_int2(s, __float_as_int(dinv[s]));
    }
}

// ---------------------------------------------------------------------------
// K4: gather-aggregate in D_IN=64 space. One wave per node, lane = column.
//     Unroll-8 over padded edge list: 8 independent row-gathers in flight.
// ---------------------------------------------------------------------------
__global__ __launch_bounds__(256) void k_gather(const int* __restrict__ rowend,
                                                const int* __restrict__ deg,
                                                const float* __restrict__ dinv,
                                                const float4* __restrict__ ep4,
                                                const float* __restrict__ x,
                                                float* __restrict__ agg, int N) {
    int wave = threadIdx.x >> 6, lane = threadIdx.x & 63;
    int n = blockIdx.x * 4 + wave;
    if (n >= N) return;
    float dn = dinv[n];
    float acc = x[(size_t)n * D_IN + lane] * dn;   // self-loop (outer dn at end)
    int end = rowend[n];
    int cnt = deg[n];
    int start = end - cnt;                          // 8-aligned padded start
    int iters = (cnt + 7) >> 3;
    const float4* p = ep4 + (start >> 1);           // 2 pairs per float4
    for (int it = 0; it < iters; ++it, p += 4) {
        float4 p01 = p[0], p23 = p[1], p45 = p[2], p67 = p[3];
        int s0 = __float_as_int(p01.x), s1 = __float_as_int(p01.z);
        int s2 = __float_as_int(p23.x), s3 = __float_as_int(p23.z);
        int s4 = __float_as_int(p45.x), s5 = __float_as_int(p45.z);
        int s6 = __float_as_int(p67.x), s7 = __float_as_int(p67.z);
        float v0 = x[(size_t)s0 * D_IN + lane];
        float v1 = x[(size_t)s1 * D_IN + lane];
        float v2 = x[(size_t)s2 * D_IN + lane];
        float v3 = x[(size_t)s3 * D_IN + lane];
        float v4 = x[(size_t)s4 * D_IN + lane];
        float v5 = x[(size_t)s5 * D_IN + lane];
        float v6 = x[(size_t)s6 * D_IN + lane];
        float v7 = x[(size_t)s7 * D_IN + lane];
        acc = fmaf(p01.y, v0, acc);
        acc = fmaf(p01.w, v1, acc);
        acc = fmaf(p23.y, v2, acc);
        acc = fmaf(p23.w, v3, acc);
        acc = fmaf(p45.y, v4, acc);
        acc = fmaf(p45.w, v5, acc);
        acc = fmaf(p67.y, v6, acc);
        acc = fmaf(p67.w, v7, acc);
    }
    agg[(size_t)n * D_IN + lane] = acc * dn;
}

// ---------------------------------------------------------------------------
// K5 (new): MFMA dual GEMM + LayerNorm + residual + SiLU.
//   Wave = one 16-node tile (N = 3125*16 exactly). 4 waves/block.
//   Weights staged once per block: bf16, TRANSPOSED [col][k], XOR-swizzled
//   (byte ^= (col&7)<<4) -> B-frag = single conflict-free ds_read_b128.
//   A-frags from global f32 + in-register bf16 convert (agg/x L2-resident).
//   mfma_f32_16x16x32_bf16: A[row=lane&15][k=(lane>>4)*8+j (+32/chunk)],
//   B[k same][col=lane&15], C/D: col=lane&15, row=(lane>>4)*4+reg (verified).
// ---------------------------------------------------------------------------
__global__ __launch_bounds__(256) void k_mfma_ln(const float* __restrict__ agg,
                                                 const float* __restrict__ x,
                                                 const float* __restrict__ W,
                                                 const float* __restrict__ rW,
                                                 const float* __restrict__ b,
                                                 const float* __restrict__ rb,
                                                 const float* __restrict__ lnw,
                                                 const float* __restrict__ lnb,
                                                 float* __restrict__ out,
                                                 int N, int NT) {
    __shared__ __align__(16) unsigned short sB[2 * 64 * 128];   // 32 KB
    unsigned* sB32 = (unsigned*)sB;

    // ---- stage W, rW -> bf16 transposed+swizzled LDS ----
    // thread t: c = t&127, kh = t>>7; k = kh*32 + 2*kk (pairs -> u32 writes)
    {
        int c = threadIdx.x & 127, kh = threadIdx.x >> 7;
#pragma unroll
        for (int kk = 0; kk < 16; kk++) {
            int k = kh * 32 + kk * 2;
            float w0 = W[k * D_OUT + c], w1 = W[(k + 1) * D_OUT + c];
            float r0 = rW[k * D_OUT + c], r1 = rW[(k + 1) * D_OUT + c];
            unsigned wp = (unsigned)f2bf(w0) | ((unsigned)f2bf(w1) << 16);
            unsigned rp = (unsigned)f2bf(r0) | ((unsigned)f2bf(r1) << 16);
            int idx = c * 32 + ((k >> 1) ^ ((c & 7) << 2));
            sB32[idx] = wp;
            sB32[4096 + idx] = rp;
        }
    }
    __syncthreads();

    int wave = threadIdx.x >> 6, lane = threadIdx.x & 63;
    int tid = blockIdx.x * 4 + wave;
    if (tid >= NT) return;

    int n0 = tid * 16;
    int arow = n0 + (lane & 15);
    if (arow >= N) arow = N - 1;                    // clamp (N%16==0 anyway)
    int kgrp = (lane >> 4) * 8;                     // 0,8,16,24

    // ---- A-frags: agg and x, chunks c=0 (k 0..31) and c=1 (k 32..63) ----
    bf16x8 aA0, aA1, aX0, aX1;
    {
        const float* pa = &agg[(size_t)arow * D_IN + kgrp];
        const float* px = &x[(size_t)arow * D_IN + kgrp];
        float4 a0 = *(const float4*)(pa);
        float4 a1 = *(const float4*)(pa + 4);
        float4 a2 = *(const float4*)(pa + 32);
        float4 a3 = *(const float4*)(pa + 36);
        float4 x0 = *(const float4*)(px);
        float4 x1 = *(const float4*)(px + 4);
        float4 x2 = *(const float4*)(px + 32);
        float4 x3 = *(const float4*)(px + 36);
        aA0[0]=f2bf(a0.x); aA0[1]=f2bf(a0.y); aA0[2]=f2bf(a0.z); aA0[3]=f2bf(a0.w);
        aA0[4]=f2bf(a1.x); aA0[5]=f2bf(a1.y); aA0[6]=f2bf(a1.z); aA0[7]=f2bf(a1.w);
        aA1[0]=f2bf(a2.x); aA1[1]=f2bf(a2.y); aA1[2]=f2bf(a2.z); aA1[3]=f2bf(a2.w);
        aA1[4]=f2bf(a3.x); aA1[5]=f2bf(a3.y); aA1[6]=f2bf(a3.z); aA1[7]=f2bf(a3.w);
        aX0[0]=f2bf(x0.x); aX0[1]=f2bf(x0.y); aX0[2]=f2bf(x0.z); aX0[3]=f2bf(x0.w);
        aX0[4]=f2bf(x1.x); aX0[5]=f2bf(x1.y); aX0[6]=f2bf(x1.z); aX0[7]=f2bf(x1.w);
        aX1[0]=f2bf(x2.x); aX1[1]=f2bf(x2.y); aX1[2]=f2bf(x2.z); aX1[3]=f2bf(x2.w);
        aX1[4]=f2bf(x3.x); aX1[5]=f2bf(x3.y); aX1[6]=f2bf(x3.z); aX1[7]=f2bf(x3.w);
    }

    // ---- MFMA: 8 col-tiles x 2 k-chunks x 2 matrices ----
    f32x4 accT[8], accU[8];
#pragma unroll
    for (int t = 0; t < 8; t++) { accT[t] = (f32x4){0.f,0.f,0.f,0.f};
                                  accU[t] = (f32x4){0.f,0.f,0.f,0.f}; }
    int cbase = lane & 15;
#pragma unroll
    for (int t = 0; t < 8; t++) {
        int col = 16 * t + cbase;
        // u16 index: (col*64 + k) ^ ((col&7)<<3); k = kgrp (+32 for chunk 1)
        int i0 = ((col * 64 + kgrp) ^ ((col & 7) << 3));
        int i1 = ((col * 64 + kgrp + 32) ^ ((col & 7) << 3));
        bf16x8 bw0 = *(const bf16x8*)&sB[i0];
        bf16x8 bw1 = *(const bf16x8*)&sB[i1];
        bf16x8 br0 = *(const bf16x8*)&sB[8192 + i0];
        bf16x8 br1 = *(const bf16x8*)&sB[8192 + i1];
        accT[t] = __builtin_amdgcn_mfma_f32_16x16x32_bf16(aA0, bw0, accT[t], 0, 0, 0);
        accT[t] = __builtin_amdgcn_mfma_f32_16x16x32_bf16(aA1, bw1, accT[t], 0, 0, 0);
        accU[t] = __builtin_amdgcn_mfma_f32_16x16x32_bf16(aX0, br0, accU[t], 0, 0, 0);
        accU[t] = __builtin_amdgcn_mfma_f32_16x16x32_bf16(aX1, br1, accU[t], 0, 0, 0);
    }

    // ---- epilogue: +b, LayerNorm rows, +x@rW+rb, SiLU, store ----
    float bv[8], rbv[8], wv[8], lbv[8];
#pragma unroll
    for (int t = 0; t < 8; t++) {
        int col = 16 * t + cbase;
        bv[t] = b[col]; rbv[t] = rb[col]; wv[t] = lnw[col]; lbv[t] = lnb[col];
    }
    float mu[4], inv[4];
#pragma unroll
    for (int r = 0; r < 4; r++) {
        float s1 = 0.f, s2 = 0.f;
#pragma unroll
        for (int t = 0; t < 8; t++) {
            float v = accT[t][r] + bv[t];
            accT[t][r] = v;
            s1 += v;
            s2 += v * v;
        }
        // reduce across the 16 lanes holding this row's 128 cols
#pragma unroll
        for (int m = 1; m < 16; m <<= 1) {
            s1 += __shfl_xor(s1, m);
            s2 += __shfl_xor(s2, m);
        }
        float m_ = s1 * (1.f / 128.f);
        float var = s2 * (1.f / 128.f) - m_ * m_;
        mu[r] = m_;
        inv[r] = rsqrtf(var + 1e-5f);
    }
    int rbase = n0 + (lane >> 4) * 4;
#pragma unroll
    for (int r = 0; r < 4; r++) {
        int rowg = rbase + r;
        if (rowg >= N) continue;
#pragma unroll
        for (int t = 0; t < 8; t++) {
            float y = (accT[t][r] - mu[r]) * inv[r] * wv[t] + lbv[t]
                      + accU[t][r] + rbv[t];
            float o = y / (1.f + expf(-y));
            out[(size_t)rowg * D_OUT + 16 * t + cbase] = o;
        }
    }
}

// ---------------------------------------------------------------------------
extern "C" void kernel_launch(void* const* d_in, const int* in_sizes, int n_in,
                              void* d_out, int out_size, void* d_ws, size_t ws_size,
                              hipStream_t stream) {
    const float* x = (const float*)d_in[0];
    const int* ei = (const int*)d_in[1];   // harness converts integer inputs to int32
    const float* W = (const float*)d_in[2];
    const float* b = (const float*)d_in[3];
    const float* lnw = (const float*)d_in[4];
    const float* lnb = (const float*)d_in[5];
    const float* rW = (const float*)d_in[6];
    const float* rb = (const float*)d_in[7];
    float* out = (float*)d_out;

    int N = in_sizes[0] / D_IN;
    int E = in_sizes[1] / 2;
    const int* esrc_in = ei;
    const int* edst_in = ei + E;

    // workspace carve-up (all 4-byte types)
    float* agg = (float*)d_ws;                  // N*64
    float* dinv = agg + (size_t)N * D_IN;       // N
    int* deg = (int*)(dinv + N);                // N
    int* row = deg + N;                         // N
    int* bsum = row + N;                        // 256
    int2* ep = (int2*)(bsum + 256);             // E + 7N + 8 pairs (padded CSR)

    size_t ep_pairs = (size_t)E + 7u * (size_t)N + 8u;

    hipMemsetAsync(deg, 0, (size_t)N * sizeof(int), stream);
    hipMemsetAsync(ep, 0, ep_pairs * sizeof(int2), stream);  // zero padding slots

    int eblk = (E + 255) / 256;
    int nblk = (N + 255) / 256;

    k_count_deg<<<eblk, 256, 0, stream>>>(edst_in, deg, E);
    k_scan_local<<<nblk, 256, 0, stream>>>(deg, dinv, row, bsum, N);
    k_scan_bsum<<<1, 256, 0, stream>>>(bsum, nblk);
    k_scan_add<<<nblk, 256, 0, stream>>>(row, bsum, N);
    k_fill_edges<<<eblk, 256, 0, stream>>>(esrc_in, edst_in, dinv, row, ep, E);
    k_gather<<<(N + 3) / 4, 256, 0, stream>>>(row, deg, dinv, (const float4*)ep, x, agg, N);

    int NT = (N + 15) / 16;
    int gblk = (NT + 3) / 4;
    k_mfma_ln<<<gblk, 256, 0, stream>>>(agg, x, W, rW, b, rb, lnw, lnb, out, N, NT);
}